// Round 6
// baseline (323.591 us; speedup 1.0000x reference)
//
#include <hip/hip_runtime.h>
#include <cstdint>

#define H_ 128
#define W_ 128
#define HW 16384

typedef _Float16 f16x8 __attribute__((ext_vector_type(8)));
typedef _Float16 f16x4 __attribute__((ext_vector_type(4)));
typedef _Float16 f16x2 __attribute__((ext_vector_type(2)));
typedef float f32x4 __attribute__((ext_vector_type(4)));

// ---------------------------------------------------------------------------
// All weight preps + input transposes in ONE launch (branch ladder on blockIdx).
// ---------------------------------------------------------------------------
__global__ __launch_bounds__(256)
void prep_all(const float* __restrict__ wd, const float* __restrict__ w1,
              const float* __restrict__ w2, const float* __restrict__ w3,
              const float* __restrict__ w4, const float* __restrict__ x,
              const float* __restrict__ ef,
              _Float16* __restrict__ wp, _Float16* __restrict__ A1,
              _Float16* __restrict__ A2, _Float16* __restrict__ A3,
              _Float16* __restrict__ A4, _Float16* __restrict__ xt,
              _Float16* __restrict__ ef_t) {
    __shared__ __align__(16) _Float16 t[128 * 200];
    const int bx  = blockIdx.x;
    const int tid = threadIdx.x;
    if (bx < 384) {                          // deform weight -> Wp[g][o][kc96]
        int i = bx * 256 + tid;
        int kc = i % 96;
        int go = i / 96;
        int o = go & 63, g = go >> 6;
        float v = 0.f;
        if (kc < 72) { int k = kc >> 3, c = kc & 7; v = wd[(o * 128 + g * 8 + c) * 9 + k]; }
        wp[i] = (_Float16)v;
    } else if (bx < 2256) {                  // conv A layouts
        const float* w; _Float16* Ap; int CIN, COUT, COpad, base;
        if (bx < 816)       { w = w1; Ap = A1; CIN = 192; COUT = 64;  COpad = 64;  base = 384; }
        else if (bx < 960)  { w = w2; Ap = A2; CIN = 64;  COUT = 64;  COpad = 64;  base = 816; }
        else if (bx < 1104) { w = w3; Ap = A3; CIN = 64;  COUT = 64;  COpad = 64;  base = 960; }
        else                { w = w4; Ap = A4; CIN = 64;  COUT = 432; COpad = 512; base = 1104; }
        int i = (bx - base) * 256 + tid;
        int kb = i / (COpad * 8);
        int rem = i - kb * (COpad * 8);
        int co = rem >> 3, j = rem & 7;
        int k = kb * 8 + j;
        int s = k / CIN;
        int ci = k - s * CIN;
        int kh = s / 3, kw = s % 3;
        float v = (co < COUT) ? w[((size_t)co * CIN + ci) * 9 + kh * 3 + kw] : 0.f;
        Ap[i] = (_Float16)v;
    } else if (bx < 6352) {                  // x -> xt[b][g][px][c8] fp16
        int i = (bx - 2256) * 256 + tid;
        int px = i & 16383;
        int g  = (i >> 14) & 15;
        int b  = i >> 18;
        const float* xp = x + ((size_t)(b * 128 + g * 8) * HW) + px;
        f16x8 v;
        #pragma unroll
        for (int c = 0; c < 8; ++c) v[c] = (_Float16)xp[c * HW];
        *(f16x8*)(xt + (size_t)i * 8) = v;
    } else {                                 // extra_feat NCHW -> NHWC fp16
        int bb = bx - 6352;
        int b = bb >> 7, h = bb & 127;
        for (int i = tid; i < 192 * 128; i += 256) {
            int c = i >> 7, w = i & 127;
            t[w * 200 + c] = (_Float16)ef[((size_t)(b * 192 + c) * 128 + h) * 128 + w];
        }
        __syncthreads();
        _Float16* ob = ef_t + ((size_t)(b * 128 + h) * 128) * 192;
        for (int i = tid; i < 128 * 24; i += 256) {
            int px = i / 24, c8 = i % 24;
            *(f16x8*)(ob + px * 192 + c8 * 8) = *(const f16x8*)(t + px * 200 + c8 * 8);
        }
    }
}

// ---------------------------------------------------------------------------
// MFMA implicit-GEMM 3x3 conv, pad 1. 64-px half-row tiles (25.3 KB LDS).
// STRAIGHT-LINE structure only: stage -> barrier -> compute -> epilogue,
// cout groups via blockIdx.y. (Rounds 2-4 proved any in-block cout-group
// loop with acc live across an epilogue either balloons VGPRs or spills.)
// ACT 1 = lrelu -> NHWC fp16. ACT 2 = conv4 epilogue (offsets+mask).
// ---------------------------------------------------------------------------
template<int CIN_T, int COUT_T, int COpad_T, int NWM, int NWN, int MT, int NT,
         int ACT, int MINW>
__global__ __launch_bounds__(256, MINW)
void conv_mfma2(const _Float16* __restrict__ in, const _Float16* __restrict__ Ap,
                const float* __restrict__ bias, void* __restrict__ outp,
                _Float16* __restrict__ mskp) {
    constexpr int PX = 64;
    static_assert(NWM * NWN == 4 && NWN * NT * 16 == PX, "tiling");
    constexpr int TW  = PX + 2;                  // 66
    constexpr int CPC = CIN_T / 8;
    constexpr int NKH = (CIN_T == 64) ? 3 : 1;
    constexpr int NST = 3 / NKH;
    constexpr int TC  = NKH * TW * CPC;          // f16x8 chunks per stage
    constexpr int COg = NWM * MT * 16;
    __shared__ __align__(16) _Float16 lds[TC * 8];

    const int tid  = threadIdx.x;
    // bijective XCD swizzle (grid x=1024): contiguous (b,h,ns) chunk per XCD.
    // y-siblings (same input tile) have linear ids 1024 apart = same XCD.
    const int bxr  = (blockIdx.x & 7) * 128 + (blockIdx.x >> 3);
    const int ns   = bxr & 1;
    const int bh   = bxr >> 1;
    const int b    = bh >> 7;
    const int h    = bh & 127;
    const int cogB = blockIdx.y * COg;
    const int wv   = tid >> 6;
    const int wv_m = wv / NWN;
    const int wv_n = wv - wv_m * NWN;
    const int lane = tid & 63;
    const int quad = lane >> 4;
    const int l16  = lane & 15;
    const int w0g  = ns * PX;

    f32x4 acc[MT][NT];
    #pragma unroll
    for (int mt = 0; mt < MT; ++mt)
        #pragma unroll
        for (int nt = 0; nt < NT; ++nt) acc[mt][nt] = (f32x4){0.f, 0.f, 0.f, 0.f};

    const _Float16* inb = in + (size_t)b * (HW * CIN_T);

    auto stage = [&](int s) {
        for (int i = tid; i < TC; i += 256) {
            int kh_l = i / (TW * CPC);
            int r2   = i - kh_l * (TW * CPC);
            int wp_  = r2 / CPC;
            int c8   = r2 - wp_ * CPC;
            int kh   = s * NKH + kh_l;
            int hh   = h - 1 + kh;
            int w    = w0g + wp_ - 1;
            f16x8 v = (f16x8){0, 0, 0, 0, 0, 0, 0, 0};
            if ((unsigned)hh < 128u && (unsigned)w < 128u)
                v = *(const f16x8*)(inb + (hh * 128 + w) * CIN_T + c8 * 8);
            int slot = (c8 & ~7) | ((c8 & 7) ^ (wp_ & 7));
            ((f16x8*)lds)[(kh_l * TW + wp_) * CPC + slot] = v;
        }
    };

    auto compute = [&](int s) {
        #pragma unroll
        for (int kh_l = 0; kh_l < NKH; ++kh_l) {
            const int kh = s * NKH + kh_l;
            #pragma unroll
            for (int kwi = 0; kwi < 3; ++kwi) {
                #pragma unroll
                for (int ci32 = 0; ci32 < CIN_T / 32; ++ci32) {
                    const int kb0 = (kh * 3 + kwi) * CPC + ci32 * 4;
                    f16x8 aF[MT];
                    #pragma unroll
                    for (int mt = 0; mt < MT; ++mt) {
                        int co_m = cogB + (wv_m * MT + mt) * 16 + l16;
                        aF[mt] = *(const f16x8*)(Ap + ((size_t)(kb0 + quad) * COpad_T + co_m) * 8);
                    }
                    const int c8v = ci32 * 4 + quad;
                    #pragma unroll
                    for (int nt = 0; nt < NT; ++nt) {
                        int n  = (wv_n * NT + nt) * 16 + l16;
                        int wq = n + kwi;
                        int slot = (c8v & ~7) | ((c8v & 7) ^ (wq & 7));
                        f16x8 bF = ((const f16x8*)lds)[(kh_l * TW + wq) * CPC + slot];
                        #pragma unroll
                        for (int mt = 0; mt < MT; ++mt)
                            acc[mt][nt] = __builtin_amdgcn_mfma_f32_16x16x32_f16(aF[mt], bF, acc[mt][nt], 0, 0, 0);
                    }
                }
            }
        }
    };

    #pragma unroll 1
    for (int s = 0; s < NST; ++s) {
        __syncthreads();
        stage(s);
        __syncthreads();
        compute(s);
    }

    if constexpr (ACT == 1) {
        _Float16* ob = (_Float16*)outp + ((size_t)((b * 128 + h) * 128) + w0g) * 64;
        #pragma unroll
        for (int mt = 0; mt < MT; ++mt) {
            int co_b = (wv_m * MT + mt) * 16 + quad * 4;
            #pragma unroll
            for (int nt = 0; nt < NT; ++nt) {
                int px = (wv_n * NT + nt) * 16 + l16;
                f16x4 sv;
                #pragma unroll
                for (int r = 0; r < 4; ++r) {
                    float v = acc[mt][nt][r] + bias[co_b + r];
                    v = v > 0.f ? v : 0.1f * v;
                    sv[r] = (_Float16)v;
                }
                *(f16x4*)(ob + px * 64 + co_b) = sv;
            }
        }
    } else {
        _Float16* off2 = (_Float16*)outp;
        const int pxbase = h * 128 + w0g;
        #pragma unroll
        for (int mt = 0; mt < MT; ++mt) {
            int co_base = cogB + (wv_m * MT + mt) * 16 + quad * 4;   // even
            #pragma unroll
            for (int r2 = 0; r2 < 2; ++r2) {
                int co0 = co_base + 2 * r2;
                if (co0 < 288) {             // offset pair (dy co0, dx co0+1)
                    int g = co0 / 18;
                    int k = (co0 - g * 18) >> 1;
                    float bv0 = bias[co0], bv1 = bias[co0 + 1];
                    #pragma unroll
                    for (int nt = 0; nt < NT; ++nt) {
                        int px = (wv_n * NT + nt) * 16 + l16;
                        float v0 = acc[mt][nt][2 * r2]     + bv0;
                        float v1 = acc[mt][nt][2 * r2 + 1] + bv1;
                        float e0 = __expf(2.f * v0);
                        float e1 = __expf(2.f * v1);
                        f16x2 ov;
                        ov[0] = (_Float16)(10.f * (1.f - 2.f / (e0 + 1.f)));
                        ov[1] = (_Float16)(10.f * (1.f - 2.f / (e1 + 1.f)));
                        *(f16x2*)(off2 + (((size_t)(b * 16 + g) * 9 + k) * HW + pxbase + px) * 2) = ov;
                    }
                } else if (co0 < 432) {      // two mask channels
                    #pragma unroll
                    for (int j = 0; j < 2; ++j) {
                        int co = co0 + j;
                        int mm = co - 288;
                        int g = mm / 9;
                        int k = mm - g * 9;
                        float bv = bias[co];
                        #pragma unroll
                        for (int nt = 0; nt < NT; ++nt) {
                            int px = (wv_n * NT + nt) * 16 + l16;
                            float v = acc[mt][nt][2 * r2 + j] + bv;
                            v = 1.f / (1.f + __expf(-v));
                            mskp[((size_t)(b * 16 + g) * 9 + k) * HW + pxbase + px] = (_Float16)v;
                        }
                    }
                }
            }
        }
    }
}

// ---------------------------------------------------------------------------
// FUSED deformable conv, 32-px quarter-row blocks. Grid 2048 -> 8 blocks/CU
// (16 KB LDS), 32 waves/CU theoretical — the r5 version was grid-limited to
// 16 waves/CU (occupancy 34%) and pure latency-bound (MfmaUtil 6.7%, HBM 9%).
// Per thread: px = tid&31, k-slot = tid>>5 (slot 0 also takes k=8).
// Same swizzled V layout (0 conflicts measured), 1 barrier/group, offsets
// prefetched one group ahead. Accumulates 64co x 32px, writes fp32 out.
// ---------------------------------------------------------------------------
__global__ __launch_bounds__(256, 4)
void deform_fused(const _Float16* __restrict__ xt, const _Float16* __restrict__ off2,
                  const _Float16* __restrict__ msk, const _Float16* __restrict__ wp,
                  const float* __restrict__ bias, float* __restrict__ out) {
    __shared__ __align__(16) char vlds[2 * 32 * 256];   // 16 KB, double-buffered
    const int tid  = threadIdx.x;
    // bijective XCD swizzle: 2048 blocks, 8 XCDs, 256 contiguous blocks each
    const int bx   = (blockIdx.x & 7) * 256 + (blockIdx.x >> 3);
    const int nq   = bx & 3;           // 32-px quarter of the row
    const int bh   = bx >> 2;
    const int b    = bh >> 7;
    const int hrow = bh & 127;
    const int wv   = tid >> 6;
    const int lane = tid & 63;
    const int quad = lane >> 4;
    const int l16  = lane & 15;

    const int pxl   = tid & 31;        // local px (V row)
    const int slot  = tid >> 5;        // k-slot 0..7 (2 slots per wave)
    const int wglob = nq * 32 + pxl;
    const int pxg   = hrow * 128 + wglob;
    const bool has2 = (slot == 0);     // slot 0 also handles k=8

    {   // zero both buffers: swizzled chunks (9..15)^sw are never written
        f32x4 z = (f32x4){0.f, 0.f, 0.f, 0.f};
        for (int i = tid; i < 1024; i += 256) ((f32x4*)vlds)[i] = z;
    }
    __syncthreads();

    const _Float16* o2b = off2 + (size_t)b * 16 * 9 * HW * 2;
    const _Float16* mb  = msk  + (size_t)b * 16 * 9 * HW;

    f32x4 acc[2];
    acc[0] = (f32x4){0.f, 0.f, 0.f, 0.f};
    acc[1] = (f32x4){0.f, 0.f, 0.f, 0.f};

    // prologue: load group-0 offsets/masks
    f16x2 od_c[2]; _Float16 m_c[2];
    od_c[0] = *(const f16x2*)(o2b + ((size_t)slot * HW + pxg) * 2);
    m_c[0]  = mb[(size_t)slot * HW + pxg];
    od_c[1] = od_c[0]; m_c[1] = m_c[0];
    if (has2) {
        od_c[1] = *(const f16x2*)(o2b + ((size_t)8 * HW + pxg) * 2);
        m_c[1]  = mb[(size_t)8 * HW + pxg];
    }

    #pragma unroll 1
    for (int gl = 0; gl < 16; ++gl) {
        const _Float16* xg = xt + ((size_t)(b * 16 + gl) * HW) * 8;
        char* vb = vlds + (gl & 1) * 8192;

        f16x8 aF[3];
        const _Float16* wg = wp + ((size_t)(gl * 64 + wv * 16 + l16)) * 96 + quad * 8;
        #pragma unroll
        for (int s = 0; s < 3; ++s) aF[s] = *(const f16x8*)(wg + s * 32);

        // prefetch next group's offsets/masks (independent of this group)
        f16x2 od_n[2]; _Float16 m_n[2];
        od_n[0] = od_c[0]; od_n[1] = od_c[1]; m_n[0] = m_c[0]; m_n[1] = m_c[1];
        if (gl < 15) {
            od_n[0] = *(const f16x2*)(o2b + ((size_t)((gl + 1) * 9 + slot) * HW + pxg) * 2);
            m_n[0]  = mb[(size_t)((gl + 1) * 9 + slot) * HW + pxg];
            if (has2) {
                od_n[1] = *(const f16x2*)(o2b + ((size_t)((gl + 1) * 9 + 8) * HW + pxg) * 2);
                m_n[1]  = mb[(size_t)((gl + 1) * 9 + 8) * HW + pxg];
            }
        }

        // gather + bilinear lerp into V tile (taps: k=slot, and k=8 on slot 0)
        #pragma unroll
        for (int i = 0; i < 2; ++i) {
            if (i == 0 || has2) {
                int k = (i == 0) ? slot : 8;
                float dy = (float)od_c[i][0];
                float dx = (float)od_c[i][1];
                float m  = (float)m_c[i];
                float py  = (float)(hrow - 1 + k / 3) + dy;
                float pxf = (float)(wglob - 1 + k % 3) + dx;
                float y0f = floorf(py), x0f = floorf(pxf);
                float ly = py - y0f, lx = pxf - x0f;
                int y0 = (int)y0f, x0 = (int)x0f;
                int y1 = y0 + 1,  x1 = x0 + 1;
                float vy0 = ((unsigned)y0 < 128u) ? 1.f : 0.f;
                float vy1 = ((unsigned)y1 < 128u) ? 1.f : 0.f;
                float vx0 = ((unsigned)x0 < 128u) ? 1.f : 0.f;
                float vx1 = ((unsigned)x1 < 128u) ? 1.f : 0.f;
                float w00 = (1.f - ly) * (1.f - lx) * vy0 * vx0 * m;
                float w01 = (1.f - ly) * lx         * vy0 * vx1 * m;
                float w10 = ly * (1.f - lx)         * vy1 * vx0 * m;
                float w11 = ly * lx                 * vy1 * vx1 * m;
                int yc0 = min(max(y0, 0), 127), yc1 = min(max(y1, 0), 127);
                int xc0 = min(max(x0, 0), 127), xc1 = min(max(x1, 0), 127);
                f16x8 c00 = *(const f16x8*)(xg + (yc0 * W_ + xc0) * 8);
                f16x8 c01 = *(const f16x8*)(xg + (yc0 * W_ + xc1) * 8);
                f16x8 c10 = *(const f16x8*)(xg + (yc1 * W_ + xc0) * 8);
                f16x8 c11 = *(const f16x8*)(xg + (yc1 * W_ + xc1) * 8);
                _Float16 h00 = (_Float16)w00, h01 = (_Float16)w01;
                _Float16 h10 = (_Float16)w10, h11 = (_Float16)w11;
                f16x8 vv = c00 * h00 + c01 * h01 + c10 * h10 + c11 * h11;  // v_pk_fma_f16
                int chunk = k ^ (pxl & 15);
                *(f16x8*)(vb + pxl * 256 + chunk * 16) = vv;
            }
        }
        __syncthreads();

        #pragma unroll
        for (int nt = 0; nt < 2; ++nt) {
            int row = nt * 16 + l16;
            int sw  = row & 15;
            #pragma unroll
            for (int s = 0; s < 3; ++s) {
                f16x8 bF = *(const f16x8*)(vb + row * 256 + (((s << 2) + quad) ^ sw) * 16);
                acc[nt] = __builtin_amdgcn_mfma_f32_16x16x32_f16(aF[s], bF, acc[nt], 0, 0, 0);
            }
        }

        od_c[0] = od_n[0]; od_c[1] = od_n[1]; m_c[0] = m_n[0]; m_c[1] = m_n[1];
    }

    // ---- epilogue: transpose 64co x 32px through LDS, coalesced fp32 stores
    __syncthreads();
    float* vf = (float*)vlds;          // 64 x 32 fp32 = 8 KB (buffer 0)
    #pragma unroll
    for (int r = 0; r < 4; ++r) {
        int o = wv * 16 + quad * 4 + r;
        #pragma unroll
        for (int nt = 0; nt < 2; ++nt) {
            int col = nt ^ (quad & 1);
            vf[o * 32 + col * 16 + l16] = acc[nt][r];
        }
    }
    __syncthreads();
    float* ob = out + ((size_t)(b * 64)) * HW + hrow * 128 + nq * 32;
    #pragma unroll
    for (int it = 0; it < 2; ++it) {
        int sl  = tid + it * 256;      // 64 o x 8 p4
        int o   = sl >> 3;
        int p4  = sl & 7;
        int col = (p4 >> 2) ^ ((o >> 2) & 1);
        f32x4 v = *(const f32x4*)(vf + o * 32 + col * 16 + (p4 & 3) * 4);
        float bv = bias[o];
        float4 sv = make_float4(v[0] + bv, v[1] + bv, v[2] + bv, v[3] + bv);
        *(float4*)(ob + (size_t)o * HW + p4 * 4) = sv;
    }
}

// ---------------------------------------------------------------------------
extern "C" void kernel_launch(void* const* d_in, const int* in_sizes, int n_in,
                              void* d_out, int out_size, void* d_ws, size_t ws_size,
                              hipStream_t stream) {
    const float* x  = (const float*)d_in[0];
    const float* ef = (const float*)d_in[1];
    const float* w1 = (const float*)d_in[2];
    const float* b1 = (const float*)d_in[3];
    const float* w2 = (const float*)d_in[4];
    const float* b2 = (const float*)d_in[5];
    const float* w3 = (const float*)d_in[6];
    const float* b3 = (const float*)d_in[7];
    const float* w4 = (const float*)d_in[8];
    const float* b4 = (const float*)d_in[9];
    const float* wd = (const float*)d_in[10];
    const float* bd = (const float*)d_in[11];
    float* out = (float*)d_out;

    char* ws = (char*)d_ws;
    _Float16* ef_t = (_Float16*)(ws);                     // 25,165,824 B
    _Float16* tA   = (_Float16*)(ws + 25165824);          //  8,388,608 B
    _Float16* tB   = (_Float16*)(ws + 33554432);          //  8,388,608 B
    _Float16* off2 = (_Float16*)(ws + 41943040);          // 37,748,736 B
    _Float16* mskb = (_Float16*)(ws + 79691776);          // 18,874,368 B
    _Float16* wpd  = (_Float16*)(ws + 98566144);          //    196,608 B
    _Float16* A1   = (_Float16*)(ws + 98762752);          //    221,184 B
    _Float16* A2   = (_Float16*)(ws + 98983936);          //     73,728 B
    _Float16* A3   = (_Float16*)(ws + 99057664);          //     73,728 B
    _Float16* A4   = (_Float16*)(ws + 99131392);          //    589,824 B
    _Float16* xtb  = (_Float16*)(ws + 99721216);          // 16,777,216 B -> ends 116,498,432

    prep_all<<<6864, 256, 0, stream>>>(wd, w1, w2, w3, w4, x, ef,
                                       wpd, A1, A2, A3, A4, xtb, ef_t);

    //            CIN  COUT COpad NWM NWN MT NT ACT MINW
    conv_mfma2<192,  64,  64,  2,  2, 2, 2, 1, 4><<<dim3(1024, 1), 256, 0, stream>>>(ef_t, A1, b1, tA, nullptr);
    conv_mfma2< 64,  64,  64,  2,  2, 2, 2, 1, 4><<<dim3(1024, 1), 256, 0, stream>>>(tA, A2, b2, tB, nullptr);
    conv_mfma2< 64,  64,  64,  2,  2, 2, 2, 1, 4><<<dim3(1024, 1), 256, 0, stream>>>(tB, A3, b3, tA, nullptr);
    conv_mfma2< 64, 432, 512,  2,  2, 4, 2, 2, 2><<<dim3(1024, 4), 256, 0, stream>>>(tA, A4, b4, off2, mskb);

    deform_fused<<<2048, 256, 0, stream>>>(xtb, off2, mskb, wpd, bd, out);
}

// Round 7
// 316.665 us; speedup vs baseline: 1.0219x; 1.0219x over previous
//
#include <hip/hip_runtime.h>
#include <cstdint>

#define H_ 128
#define W_ 128
#define HW 16384

typedef _Float16 f16x8 __attribute__((ext_vector_type(8)));
typedef _Float16 f16x4 __attribute__((ext_vector_type(4)));
typedef _Float16 f16x2 __attribute__((ext_vector_type(2)));
typedef float f32x4 __attribute__((ext_vector_type(4)));

// ---------------------------------------------------------------------------
// All weight preps + input transposes in ONE launch (branch ladder on blockIdx).
// ---------------------------------------------------------------------------
__global__ __launch_bounds__(256)
void prep_all(const float* __restrict__ wd, const float* __restrict__ w1,
              const float* __restrict__ w2, const float* __restrict__ w3,
              const float* __restrict__ w4, const float* __restrict__ x,
              const float* __restrict__ ef,
              _Float16* __restrict__ wp, _Float16* __restrict__ A1,
              _Float16* __restrict__ A2, _Float16* __restrict__ A3,
              _Float16* __restrict__ A4, _Float16* __restrict__ xt,
              _Float16* __restrict__ ef_t) {
    __shared__ __align__(16) _Float16 t[128 * 200];
    const int bx  = blockIdx.x;
    const int tid = threadIdx.x;
    if (bx < 384) {                          // deform weight -> Wp[g][o][kc96]
        int i = bx * 256 + tid;
        int kc = i % 96;
        int go = i / 96;
        int o = go & 63, g = go >> 6;
        float v = 0.f;
        if (kc < 72) { int k = kc >> 3, c = kc & 7; v = wd[(o * 128 + g * 8 + c) * 9 + k]; }
        wp[i] = (_Float16)v;
    } else if (bx < 2256) {                  // conv A layouts
        const float* w; _Float16* Ap; int CIN, COUT, COpad, base;
        if (bx < 816)       { w = w1; Ap = A1; CIN = 192; COUT = 64;  COpad = 64;  base = 384; }
        else if (bx < 960)  { w = w2; Ap = A2; CIN = 64;  COUT = 64;  COpad = 64;  base = 816; }
        else if (bx < 1104) { w = w3; Ap = A3; CIN = 64;  COUT = 64;  COpad = 64;  base = 960; }
        else                { w = w4; Ap = A4; CIN = 64;  COUT = 432; COpad = 512; base = 1104; }
        int i = (bx - base) * 256 + tid;
        int kb = i / (COpad * 8);
        int rem = i - kb * (COpad * 8);
        int co = rem >> 3, j = rem & 7;
        int k = kb * 8 + j;
        int s = k / CIN;
        int ci = k - s * CIN;
        int kh = s / 3, kw = s % 3;
        float v = (co < COUT) ? w[((size_t)co * CIN + ci) * 9 + kh * 3 + kw] : 0.f;
        Ap[i] = (_Float16)v;
    } else if (bx < 6352) {                  // x -> xt[b][g][px][c8] fp16
        int i = (bx - 2256) * 256 + tid;
        int px = i & 16383;
        int g  = (i >> 14) & 15;
        int b  = i >> 18;
        const float* xp = x + ((size_t)(b * 128 + g * 8) * HW) + px;
        f16x8 v;
        #pragma unroll
        for (int c = 0; c < 8; ++c) v[c] = (_Float16)xp[c * HW];
        *(f16x8*)(xt + (size_t)i * 8) = v;
    } else {                                 // extra_feat NCHW -> NHWC fp16
        int bb = bx - 6352;
        int b = bb >> 7, h = bb & 127;
        for (int i = tid; i < 192 * 128; i += 256) {
            int c = i >> 7, w = i & 127;
            t[w * 200 + c] = (_Float16)ef[((size_t)(b * 192 + c) * 128 + h) * 128 + w];
        }
        __syncthreads();
        _Float16* ob = ef_t + ((size_t)(b * 128 + h) * 128) * 192;
        for (int i = tid; i < 128 * 24; i += 256) {
            int px = i / 24, c8 = i % 24;
            *(f16x8*)(ob + px * 192 + c8 * 8) = *(const f16x8*)(t + px * 200 + c8 * 8);
        }
    }
}

// ---------------------------------------------------------------------------
// MFMA implicit-GEMM 3x3 conv, pad 1. 64-px half-row tiles (25.3 KB LDS).
// STRAIGHT-LINE structure only: stage -> barrier -> compute -> epilogue,
// cout groups via blockIdx.y. (Rounds 2-4 proved any in-block cout-group
// loop with acc live across an epilogue either balloons VGPRs or spills.)
// ACT 1 = lrelu -> NHWC fp16. ACT 2 = conv4 epilogue (offsets+mask).
// ---------------------------------------------------------------------------
template<int CIN_T, int COUT_T, int COpad_T, int NWM, int NWN, int MT, int NT,
         int ACT, int MINW>
__global__ __launch_bounds__(256, MINW)
void conv_mfma2(const _Float16* __restrict__ in, const _Float16* __restrict__ Ap,
                const float* __restrict__ bias, void* __restrict__ outp,
                _Float16* __restrict__ mskp) {
    constexpr int PX = 64;
    static_assert(NWM * NWN == 4 && NWN * NT * 16 == PX, "tiling");
    constexpr int TW  = PX + 2;                  // 66
    constexpr int CPC = CIN_T / 8;
    constexpr int NKH = (CIN_T == 64) ? 3 : 1;
    constexpr int NST = 3 / NKH;
    constexpr int TC  = NKH * TW * CPC;          // f16x8 chunks per stage
    constexpr int COg = NWM * MT * 16;
    __shared__ __align__(16) _Float16 lds[TC * 8];

    const int tid  = threadIdx.x;
    // bijective XCD swizzle (grid x=1024): contiguous (b,h,ns) chunk per XCD.
    // y-siblings (same input tile) have linear ids 1024 apart = same XCD.
    const int bxr  = (blockIdx.x & 7) * 128 + (blockIdx.x >> 3);
    const int ns   = bxr & 1;
    const int bh   = bxr >> 1;
    const int b    = bh >> 7;
    const int h    = bh & 127;
    const int cogB = blockIdx.y * COg;
    const int wv   = tid >> 6;
    const int wv_m = wv / NWN;
    const int wv_n = wv - wv_m * NWN;
    const int lane = tid & 63;
    const int quad = lane >> 4;
    const int l16  = lane & 15;
    const int w0g  = ns * PX;

    f32x4 acc[MT][NT];
    #pragma unroll
    for (int mt = 0; mt < MT; ++mt)
        #pragma unroll
        for (int nt = 0; nt < NT; ++nt) acc[mt][nt] = (f32x4){0.f, 0.f, 0.f, 0.f};

    const _Float16* inb = in + (size_t)b * (HW * CIN_T);

    auto stage = [&](int s) {
        for (int i = tid; i < TC; i += 256) {
            int kh_l = i / (TW * CPC);
            int r2   = i - kh_l * (TW * CPC);
            int wp_  = r2 / CPC;
            int c8   = r2 - wp_ * CPC;
            int kh   = s * NKH + kh_l;
            int hh   = h - 1 + kh;
            int w    = w0g + wp_ - 1;
            f16x8 v = (f16x8){0, 0, 0, 0, 0, 0, 0, 0};
            if ((unsigned)hh < 128u && (unsigned)w < 128u)
                v = *(const f16x8*)(inb + (hh * 128 + w) * CIN_T + c8 * 8);
            int slot = (c8 & ~7) | ((c8 & 7) ^ (wp_ & 7));
            ((f16x8*)lds)[(kh_l * TW + wp_) * CPC + slot] = v;
        }
    };

    auto compute = [&](int s) {
        #pragma unroll
        for (int kh_l = 0; kh_l < NKH; ++kh_l) {
            const int kh = s * NKH + kh_l;
            #pragma unroll
            for (int kwi = 0; kwi < 3; ++kwi) {
                #pragma unroll
                for (int ci32 = 0; ci32 < CIN_T / 32; ++ci32) {
                    const int kb0 = (kh * 3 + kwi) * CPC + ci32 * 4;
                    f16x8 aF[MT];
                    #pragma unroll
                    for (int mt = 0; mt < MT; ++mt) {
                        int co_m = cogB + (wv_m * MT + mt) * 16 + l16;
                        aF[mt] = *(const f16x8*)(Ap + ((size_t)(kb0 + quad) * COpad_T + co_m) * 8);
                    }
                    const int c8v = ci32 * 4 + quad;
                    #pragma unroll
                    for (int nt = 0; nt < NT; ++nt) {
                        int n  = (wv_n * NT + nt) * 16 + l16;
                        int wq = n + kwi;
                        int slot = (c8v & ~7) | ((c8v & 7) ^ (wq & 7));
                        f16x8 bF = ((const f16x8*)lds)[(kh_l * TW + wq) * CPC + slot];
                        #pragma unroll
                        for (int mt = 0; mt < MT; ++mt)
                            acc[mt][nt] = __builtin_amdgcn_mfma_f32_16x16x32_f16(aF[mt], bF, acc[mt][nt], 0, 0, 0);
                    }
                }
            }
        }
    };

    #pragma unroll 1
    for (int s = 0; s < NST; ++s) {
        __syncthreads();
        stage(s);
        __syncthreads();
        compute(s);
    }

    if constexpr (ACT == 1) {
        _Float16* ob = (_Float16*)outp + ((size_t)((b * 128 + h) * 128) + w0g) * 64;
        #pragma unroll
        for (int mt = 0; mt < MT; ++mt) {
            int co_b = (wv_m * MT + mt) * 16 + quad * 4;
            #pragma unroll
            for (int nt = 0; nt < NT; ++nt) {
                int px = (wv_n * NT + nt) * 16 + l16;
                f16x4 sv;
                #pragma unroll
                for (int r = 0; r < 4; ++r) {
                    float v = acc[mt][nt][r] + bias[co_b + r];
                    v = v > 0.f ? v : 0.1f * v;
                    sv[r] = (_Float16)v;
                }
                *(f16x4*)(ob + px * 64 + co_b) = sv;
            }
        }
    } else {
        _Float16* off2 = (_Float16*)outp;
        const int pxbase = h * 128 + w0g;
        #pragma unroll
        for (int mt = 0; mt < MT; ++mt) {
            int co_base = cogB + (wv_m * MT + mt) * 16 + quad * 4;   // even
            #pragma unroll
            for (int r2 = 0; r2 < 2; ++r2) {
                int co0 = co_base + 2 * r2;
                if (co0 < 288) {             // offset pair (dy co0, dx co0+1)
                    int g = co0 / 18;
                    int k = (co0 - g * 18) >> 1;
                    float bv0 = bias[co0], bv1 = bias[co0 + 1];
                    #pragma unroll
                    for (int nt = 0; nt < NT; ++nt) {
                        int px = (wv_n * NT + nt) * 16 + l16;
                        float v0 = acc[mt][nt][2 * r2]     + bv0;
                        float v1 = acc[mt][nt][2 * r2 + 1] + bv1;
                        float e0 = __expf(2.f * v0);
                        float e1 = __expf(2.f * v1);
                        f16x2 ov;
                        ov[0] = (_Float16)(10.f * (1.f - 2.f / (e0 + 1.f)));
                        ov[1] = (_Float16)(10.f * (1.f - 2.f / (e1 + 1.f)));
                        *(f16x2*)(off2 + (((size_t)(b * 16 + g) * 9 + k) * HW + pxbase + px) * 2) = ov;
                    }
                } else if (co0 < 432) {      // two mask channels
                    #pragma unroll
                    for (int j = 0; j < 2; ++j) {
                        int co = co0 + j;
                        int mm = co - 288;
                        int g = mm / 9;
                        int k = mm - g * 9;
                        float bv = bias[co];
                        #pragma unroll
                        for (int nt = 0; nt < NT; ++nt) {
                            int px = (wv_n * NT + nt) * 16 + l16;
                            float v = acc[mt][nt][2 * r2 + j] + bv;
                            v = 1.f / (1.f + __expf(-v));
                            mskp[((size_t)(b * 16 + g) * 9 + k) * HW + pxbase + px] = (_Float16)v;
                        }
                    }
                }
            }
        }
    }
}

// ---------------------------------------------------------------------------
// FUSED deformable conv, r5 64-px geometry + issue-all/finish-all gathers.
// r5/r6 bug: per-tap loop's ds_write consumed that tap's 4 corner loads,
// draining vmcnt before the next tap's loads issued (MLP=4, x2-3 serial
// latencies per group). Now: ALL tap addresses+weights computed, ALL 8-12
// corner loads issued with no consumer in between (compiler keeps them in
// flight), then all lerps+LDS writes. issue(gl+1) is placed after the
// barrier, before MFMA(gl), so the next group's gather latency hides under
// the MFMA phase too. Double-buffered LDS, 1 barrier/group (race-free).
// ---------------------------------------------------------------------------
__global__ __launch_bounds__(256, 4)
void deform_fused(const _Float16* __restrict__ xt, const _Float16* __restrict__ off2,
                  const _Float16* __restrict__ msk, const _Float16* __restrict__ wp,
                  const float* __restrict__ bias, float* __restrict__ out) {
    __shared__ __align__(16) char vlds[2 * 64 * 256];   // 32 KB, double-buffered
    const int tid  = threadIdx.x;
    const int bx   = (blockIdx.x & 7) * 128 + (blockIdx.x >> 3);
    const int ns   = bx & 1;
    const int bh   = bx >> 1;
    const int b    = bh >> 7;
    const int hrow = bh & 127;
    const int wv   = tid >> 6;
    const int lane = tid & 63;
    const int quad = lane >> 4;
    const int l16  = lane & 15;

    const int pxl   = tid & 63;        // local px (V row)
    const int kq    = tid >> 6;        // k-quarter (wave-uniform)
    const int wglob = ns * 64 + pxl;
    const int pxg   = hrow * 128 + wglob;

    {   // zero both buffers: swizzled chunks (9..11)^sw are never written
        f32x4 z = (f32x4){0.f, 0.f, 0.f, 0.f};
        for (int i = tid; i < 2048; i += 256) ((f32x4*)vlds)[i] = z;
    }
    __syncthreads();

    const _Float16* o2b = off2 + (size_t)b * 16 * 9 * HW * 2;
    const _Float16* mb  = msk  + (size_t)b * 16 * 9 * HW;

    f32x4 acc[4];
    #pragma unroll
    for (int nt = 0; nt < 4; ++nt) acc[nt] = (f32x4){0.f, 0.f, 0.f, 0.f};

    // LDS chunk byte offsets are group-invariant
    int ch[3];
    #pragma unroll
    for (int i = 0; i < 3; ++i) ch[i] = (((kq + 4 * i) ^ (pxl & 15)) << 4);

    // in-flight gather state (3 taps x 4 corners)
    f16x8 g00[3], g01[3], g10[3], g11[3];
    _Float16 h00[3], h01[3], h10[3], h11[3];

    // issue: compute all tap addrs+weights, fire all loads (no consumers here)
    auto issue = [&](int gl, const f16x2* od, const _Float16* m) {
        const _Float16* xg = xt + ((size_t)(b * 16 + gl) * HW) * 8;
        #pragma unroll
        for (int i = 0; i < 3; ++i) {
            int k = kq + 4 * i;
            if (k < 9) {
                float dy = (float)od[i][0];
                float dx = (float)od[i][1];
                float mm = (float)m[i];
                float py  = (float)(hrow - 1 + k / 3) + dy;
                float pxf = (float)(wglob - 1 + k % 3) + dx;
                float y0f = floorf(py), x0f = floorf(pxf);
                float ly = py - y0f, lx = pxf - x0f;
                int y0 = (int)y0f, x0 = (int)x0f;
                int y1 = y0 + 1,  x1 = x0 + 1;
                float vy0 = ((unsigned)y0 < 128u) ? 1.f : 0.f;
                float vy1 = ((unsigned)y1 < 128u) ? 1.f : 0.f;
                float vx0 = ((unsigned)x0 < 128u) ? 1.f : 0.f;
                float vx1 = ((unsigned)x1 < 128u) ? 1.f : 0.f;
                h00[i] = (_Float16)((1.f - ly) * (1.f - lx) * vy0 * vx0 * mm);
                h01[i] = (_Float16)((1.f - ly) * lx         * vy0 * vx1 * mm);
                h10[i] = (_Float16)(ly * (1.f - lx)         * vy1 * vx0 * mm);
                h11[i] = (_Float16)(ly * lx                 * vy1 * vx1 * mm);
                int yc0 = min(max(y0, 0), 127), yc1 = min(max(y1, 0), 127);
                int xc0 = min(max(x0, 0), 127), xc1 = min(max(x1, 0), 127);
                g00[i] = *(const f16x8*)(xg + (yc0 * W_ + xc0) * 8);
                g01[i] = *(const f16x8*)(xg + (yc0 * W_ + xc1) * 8);
                g10[i] = *(const f16x8*)(xg + (yc1 * W_ + xc0) * 8);
                g11[i] = *(const f16x8*)(xg + (yc1 * W_ + xc1) * 8);
            }
        }
    };

    // finish: lerp all taps, write V tile
    auto finish = [&](int gl) {
        char* vb = vlds + (gl & 1) * 16384;
        #pragma unroll
        for (int i = 0; i < 3; ++i) {
            int k = kq + 4 * i;
            if (k < 9) {
                f16x8 vv = g00[i] * h00[i] + g01[i] * h01[i]
                         + g10[i] * h10[i] + g11[i] * h11[i];   // v_pk_fma_f16
                *(f16x8*)(vb + pxl * 256 + ch[i]) = vv;
            }
        }
    };

    // prologue: offsets + gathers for group 0
    {
        f16x2 od0[3]; _Float16 m0[3];
        #pragma unroll
        for (int i = 0; i < 3; ++i) {
            od0[i] = (f16x2){0, 0}; m0[i] = (_Float16)0.f;
            int k = kq + 4 * i;
            if (k < 9) {
                od0[i] = *(const f16x2*)(o2b + ((size_t)k * HW + pxg) * 2);
                m0[i]  = mb[(size_t)k * HW + pxg];
            }
        }
        issue(0, od0, m0);
    }

    #pragma unroll 1
    for (int gl = 0; gl < 16; ++gl) {
        // prefetch offsets/masks for gl+1 (independent; long latency OK)
        f16x2 od_n[3]; _Float16 m_n[3];
        #pragma unroll
        for (int i = 0; i < 3; ++i) { od_n[i] = (f16x2){0, 0}; m_n[i] = (_Float16)0.f; }
        if (gl < 15) {
            #pragma unroll
            for (int i = 0; i < 3; ++i) {
                int k = kq + 4 * i;
                if (k < 9) {
                    od_n[i] = *(const f16x2*)(o2b + ((size_t)((gl + 1) * 9 + k) * HW + pxg) * 2);
                    m_n[i]  = mb[(size_t)((gl + 1) * 9 + k) * HW + pxg];
                }
            }
        }

        // weight fragments for this group (L2-resident)
        f16x8 aF[3];
        const _Float16* wg = wp + ((size_t)(gl * 64 + wv * 16 + l16)) * 96 + quad * 8;
        #pragma unroll
        for (int s = 0; s < 3; ++s) aF[s] = *(const f16x8*)(wg + s * 32);

        finish(gl);                    // wait gathers, lerp, write vb[gl&1]
        __syncthreads();

        if (gl < 15) issue(gl + 1, od_n, m_n);   // loads fly during MFMA

        char* vb = vlds + (gl & 1) * 16384;
        #pragma unroll
        for (int nt = 0; nt < 4; ++nt) {
            int row = nt * 16 + l16;
            int sw  = row & 15;
            #pragma unroll
            for (int s = 0; s < 3; ++s) {
                f16x8 bF = *(const f16x8*)(vb + row * 256 + (((s << 2) + quad) ^ sw) * 16);
                acc[nt] = __builtin_amdgcn_mfma_f32_16x16x32_f16(aF[s], bF, acc[nt], 0, 0, 0);
            }
        }
    }

    // ---- epilogue: transpose 64co x 64px through LDS, coalesced fp32 stores
    __syncthreads();
    float* vf = (float*)vlds;
    #pragma unroll
    for (int r = 0; r < 4; ++r) {
        int o = wv * 16 + quad * 4 + r;
        #pragma unroll
        for (int nt = 0; nt < 4; ++nt) {
            int col = nt ^ quad;
            vf[o * 64 + col * 16 + l16] = acc[nt][r];
        }
    }
    __syncthreads();
    float* ob = out + ((size_t)(b * 64)) * HW + hrow * 128 + ns * 64;
    #pragma unroll
    for (int it = 0; it < 4; ++it) {
        int slot = tid + it * 256;
        int o    = slot >> 4;
        int p4   = slot & 15;
        int col  = (p4 >> 2) ^ ((o >> 2) & 3);
        f32x4 v = *(const f32x4*)(vf + o * 64 + col * 16 + (p4 & 3) * 4);
        float bv = bias[o];
        float4 sv = make_float4(v[0] + bv, v[1] + bv, v[2] + bv, v[3] + bv);
        *(float4*)(ob + (size_t)o * HW + p4 * 4) = sv;
    }
}

// ---------------------------------------------------------------------------
extern "C" void kernel_launch(void* const* d_in, const int* in_sizes, int n_in,
                              void* d_out, int out_size, void* d_ws, size_t ws_size,
                              hipStream_t stream) {
    const float* x  = (const float*)d_in[0];
    const float* ef = (const float*)d_in[1];
    const float* w1 = (const float*)d_in[2];
    const float* b1 = (const float*)d_in[3];
    const float* w2 = (const float*)d_in[4];
    const float* b2 = (const float*)d_in[5];
    const float* w3 = (const float*)d_in[6];
    const float* b3 = (const float*)d_in[7];
    const float* w4 = (const float*)d_in[8];
    const float* b4 = (const float*)d_in[9];
    const float* wd = (const float*)d_in[10];
    const float* bd = (const float*)d_in[11];
    float* out = (float*)d_out;

    char* ws = (char*)d_ws;
    _Float16* ef_t = (_Float16*)(ws);                     // 25,165,824 B
    _Float16* tA   = (_Float16*)(ws + 25165824);          //  8,388,608 B
    _Float16* tB   = (_Float16*)(ws + 33554432);          //  8,388,608 B
    _Float16* off2 = (_Float16*)(ws + 41943040);          // 37,748,736 B
    _Float16* mskb = (_Float16*)(ws + 79691776);          // 18,874,368 B
    _Float16* wpd  = (_Float16*)(ws + 98566144);          //    196,608 B
    _Float16* A1   = (_Float16*)(ws + 98762752);          //    221,184 B
    _Float16* A2   = (_Float16*)(ws + 98983936);          //     73,728 B
    _Float16* A3   = (_Float16*)(ws + 99057664);          //     73,728 B
    _Float16* A4   = (_Float16*)(ws + 99131392);          //    589,824 B
    _Float16* xtb  = (_Float16*)(ws + 99721216);          // 16,777,216 B -> ends 116,498,432

    prep_all<<<6864, 256, 0, stream>>>(wd, w1, w2, w3, w4, x, ef,
                                       wpd, A1, A2, A3, A4, xtb, ef_t);

    //            CIN  COUT COpad NWM NWN MT NT ACT MINW
    conv_mfma2<192,  64,  64,  2,  2, 2, 2, 1, 4><<<dim3(1024, 1), 256, 0, stream>>>(ef_t, A1, b1, tA, nullptr);
    conv_mfma2< 64,  64,  64,  2,  2, 2, 2, 1, 4><<<dim3(1024, 1), 256, 0, stream>>>(tA, A2, b2, tB, nullptr);
    conv_mfma2< 64,  64,  64,  2,  2, 2, 2, 1, 4><<<dim3(1024, 1), 256, 0, stream>>>(tB, A3, b3, tA, nullptr);
    conv_mfma2< 64, 432, 512,  2,  2, 4, 2, 2, 2><<<dim3(1024, 4), 256, 0, stream>>>(tA, A4, b4, off2, mskb);

    deform_fused<<<1024, 256, 0, stream>>>(xtb, off2, mskb, wpd, bd, out);
}

// Round 8
// 309.055 us; speedup vs baseline: 1.0470x; 1.0246x over previous
//
#include <hip/hip_runtime.h>
#include <cstdint>

#define H_ 128
#define W_ 128
#define HW 16384

typedef _Float16 f16x8 __attribute__((ext_vector_type(8)));
typedef _Float16 f16x4 __attribute__((ext_vector_type(4)));
typedef _Float16 f16x2 __attribute__((ext_vector_type(2)));
typedef float f32x4 __attribute__((ext_vector_type(4)));

// ---------------------------------------------------------------------------
// All weight preps + input transposes in ONE launch (branch ladder on blockIdx).
// ---------------------------------------------------------------------------
__global__ __launch_bounds__(256)
void prep_all(const float* __restrict__ wd, const float* __restrict__ w1,
              const float* __restrict__ w2, const float* __restrict__ w3,
              const float* __restrict__ w4, const float* __restrict__ x,
              const float* __restrict__ ef,
              _Float16* __restrict__ wp, _Float16* __restrict__ A1,
              _Float16* __restrict__ A2, _Float16* __restrict__ A3,
              _Float16* __restrict__ A4, _Float16* __restrict__ xt,
              _Float16* __restrict__ ef_t) {
    __shared__ __align__(16) _Float16 t[128 * 200];
    const int bx  = blockIdx.x;
    const int tid = threadIdx.x;
    if (bx < 384) {                          // deform weight -> Wp[g][o][kc96]
        int i = bx * 256 + tid;
        int kc = i % 96;
        int go = i / 96;
        int o = go & 63, g = go >> 6;
        float v = 0.f;
        if (kc < 72) { int k = kc >> 3, c = kc & 7; v = wd[(o * 128 + g * 8 + c) * 9 + k]; }
        wp[i] = (_Float16)v;
    } else if (bx < 2256) {                  // conv A layouts
        const float* w; _Float16* Ap; int CIN, COUT, COpad, base;
        if (bx < 816)       { w = w1; Ap = A1; CIN = 192; COUT = 64;  COpad = 64;  base = 384; }
        else if (bx < 960)  { w = w2; Ap = A2; CIN = 64;  COUT = 64;  COpad = 64;  base = 816; }
        else if (bx < 1104) { w = w3; Ap = A3; CIN = 64;  COUT = 64;  COpad = 64;  base = 960; }
        else                { w = w4; Ap = A4; CIN = 64;  COUT = 432; COpad = 512; base = 1104; }
        int i = (bx - base) * 256 + tid;
        int kb = i / (COpad * 8);
        int rem = i - kb * (COpad * 8);
        int co = rem >> 3, j = rem & 7;
        int k = kb * 8 + j;
        int s = k / CIN;
        int ci = k - s * CIN;
        int kh = s / 3, kw = s % 3;
        float v = (co < COUT) ? w[((size_t)co * CIN + ci) * 9 + kh * 3 + kw] : 0.f;
        Ap[i] = (_Float16)v;
    } else if (bx < 6352) {                  // x -> xt[b][g][px][c8] fp16
        int i = (bx - 2256) * 256 + tid;
        int px = i & 16383;
        int g  = (i >> 14) & 15;
        int b  = i >> 18;
        const float* xp = x + ((size_t)(b * 128 + g * 8) * HW) + px;
        f16x8 v;
        #pragma unroll
        for (int c = 0; c < 8; ++c) v[c] = (_Float16)xp[c * HW];
        *(f16x8*)(xt + (size_t)i * 8) = v;
    } else {                                 // extra_feat NCHW -> NHWC fp16
        int bb = bx - 6352;
        int b = bb >> 7, h = bb & 127;
        for (int i = tid; i < 192 * 128; i += 256) {
            int c = i >> 7, w = i & 127;
            t[w * 200 + c] = (_Float16)ef[((size_t)(b * 192 + c) * 128 + h) * 128 + w];
        }
        __syncthreads();
        _Float16* ob = ef_t + ((size_t)(b * 128 + h) * 128) * 192;
        for (int i = tid; i < 128 * 24; i += 256) {
            int px = i / 24, c8 = i % 24;
            *(f16x8*)(ob + px * 192 + c8 * 8) = *(const f16x8*)(t + px * 200 + c8 * 8);
        }
    }
}

// ---------------------------------------------------------------------------
// MFMA implicit-GEMM 3x3 conv, pad 1. 64-px half-row tiles (25.3 KB LDS).
// STRAIGHT-LINE structure only: stage -> barrier -> compute -> epilogue,
// cout groups via blockIdx.y. (Rounds 2-4 proved any in-block cout-group
// loop with acc live across an epilogue either balloons VGPRs or spills.)
// conv4 tile: MT=4/NT=4 (acc[4][4]=64 f32 — r1-proven 96 VGPR straight-line)
// to fix the 2:1 VALU:MFMA issue ratio measured in r7 (20% MfmaUtil, 41%
// VALUBusy): 16 MFMA per 8 address-calcs instead of 8 per 6.
// ACT 1 = lrelu -> NHWC fp16. ACT 2 = conv4 epilogue (offsets+mask).
// ---------------------------------------------------------------------------
template<int CIN_T, int COUT_T, int COpad_T, int NWM, int NWN, int MT, int NT,
         int ACT, int MINW>
__global__ __launch_bounds__(256, MINW)
void conv_mfma2(const _Float16* __restrict__ in, const _Float16* __restrict__ Ap,
                const float* __restrict__ bias, void* __restrict__ outp,
                _Float16* __restrict__ mskp) {
    constexpr int PX = 64;
    static_assert(NWM * NWN == 4 && NWN * NT * 16 == PX, "tiling");
    constexpr int TW  = PX + 2;                  // 66
    constexpr int CPC = CIN_T / 8;
    constexpr int NKH = (CIN_T == 64) ? 3 : 1;
    constexpr int NST = 3 / NKH;
    constexpr int TC  = NKH * TW * CPC;          // f16x8 chunks per stage
    constexpr int COg = NWM * MT * 16;
    __shared__ __align__(16) _Float16 lds[TC * 8];

    const int tid  = threadIdx.x;
    // bijective XCD swizzle (grid x=1024): contiguous (b,h,ns) chunk per XCD.
    // y-siblings (same input tile) have linear ids 1024 apart = same XCD.
    const int bxr  = (blockIdx.x & 7) * 128 + (blockIdx.x >> 3);
    const int ns   = bxr & 1;
    const int bh   = bxr >> 1;
    const int b    = bh >> 7;
    const int h    = bh & 127;
    const int cogB = blockIdx.y * COg;
    const int wv   = tid >> 6;
    const int wv_m = wv / NWN;
    const int wv_n = wv - wv_m * NWN;
    const int lane = tid & 63;
    const int quad = lane >> 4;
    const int l16  = lane & 15;
    const int w0g  = ns * PX;

    f32x4 acc[MT][NT];
    #pragma unroll
    for (int mt = 0; mt < MT; ++mt)
        #pragma unroll
        for (int nt = 0; nt < NT; ++nt) acc[mt][nt] = (f32x4){0.f, 0.f, 0.f, 0.f};

    const _Float16* inb = in + (size_t)b * (HW * CIN_T);

    auto stage = [&](int s) {
        for (int i = tid; i < TC; i += 256) {
            int kh_l = i / (TW * CPC);
            int r2   = i - kh_l * (TW * CPC);
            int wp_  = r2 / CPC;
            int c8   = r2 - wp_ * CPC;
            int kh   = s * NKH + kh_l;
            int hh   = h - 1 + kh;
            int w    = w0g + wp_ - 1;
            f16x8 v = (f16x8){0, 0, 0, 0, 0, 0, 0, 0};
            if ((unsigned)hh < 128u && (unsigned)w < 128u)
                v = *(const f16x8*)(inb + (hh * 128 + w) * CIN_T + c8 * 8);
            int slot = (c8 & ~7) | ((c8 & 7) ^ (wp_ & 7));
            ((f16x8*)lds)[(kh_l * TW + wp_) * CPC + slot] = v;
        }
    };

    auto compute = [&](int s) {
        #pragma unroll
        for (int kh_l = 0; kh_l < NKH; ++kh_l) {
            const int kh = s * NKH + kh_l;
            #pragma unroll
            for (int kwi = 0; kwi < 3; ++kwi) {
                #pragma unroll
                for (int ci32 = 0; ci32 < CIN_T / 32; ++ci32) {
                    const int kb0 = (kh * 3 + kwi) * CPC + ci32 * 4;
                    f16x8 aF[MT];
                    #pragma unroll
                    for (int mt = 0; mt < MT; ++mt) {
                        int co_m = cogB + (wv_m * MT + mt) * 16 + l16;
                        aF[mt] = *(const f16x8*)(Ap + ((size_t)(kb0 + quad) * COpad_T + co_m) * 8);
                    }
                    const int c8v = ci32 * 4 + quad;
                    #pragma unroll
                    for (int nt = 0; nt < NT; ++nt) {
                        int n  = (wv_n * NT + nt) * 16 + l16;
                        int wq = n + kwi;
                        int slot = (c8v & ~7) | ((c8v & 7) ^ (wq & 7));
                        f16x8 bF = ((const f16x8*)lds)[(kh_l * TW + wq) * CPC + slot];
                        #pragma unroll
                        for (int mt = 0; mt < MT; ++mt)
                            acc[mt][nt] = __builtin_amdgcn_mfma_f32_16x16x32_f16(aF[mt], bF, acc[mt][nt], 0, 0, 0);
                    }
                }
            }
        }
    };

    #pragma unroll 1
    for (int s = 0; s < NST; ++s) {
        __syncthreads();
        stage(s);
        __syncthreads();
        compute(s);
    }

    if constexpr (ACT == 1) {
        _Float16* ob = (_Float16*)outp + ((size_t)((b * 128 + h) * 128) + w0g) * 64;
        #pragma unroll
        for (int mt = 0; mt < MT; ++mt) {
            int co_b = (wv_m * MT + mt) * 16 + quad * 4;
            #pragma unroll
            for (int nt = 0; nt < NT; ++nt) {
                int px = (wv_n * NT + nt) * 16 + l16;
                f16x4 sv;
                #pragma unroll
                for (int r = 0; r < 4; ++r) {
                    float v = acc[mt][nt][r] + bias[co_b + r];
                    v = v > 0.f ? v : 0.1f * v;
                    sv[r] = (_Float16)v;
                }
                *(f16x4*)(ob + px * 64 + co_b) = sv;
            }
        }
    } else {
        _Float16* off2 = (_Float16*)outp;
        const int pxbase = h * 128 + w0g;
        #pragma unroll
        for (int mt = 0; mt < MT; ++mt) {
            int co_base = cogB + (wv_m * MT + mt) * 16 + quad * 4;   // even
            #pragma unroll
            for (int r2 = 0; r2 < 2; ++r2) {
                int co0 = co_base + 2 * r2;
                if (co0 < 288) {             // offset pair (dy co0, dx co0+1)
                    int g = co0 / 18;
                    int k = (co0 - g * 18) >> 1;
                    float bv0 = bias[co0], bv1 = bias[co0 + 1];
                    #pragma unroll
                    for (int nt = 0; nt < NT; ++nt) {
                        int px = (wv_n * NT + nt) * 16 + l16;
                        float v0 = acc[mt][nt][2 * r2]     + bv0;
                        float v1 = acc[mt][nt][2 * r2 + 1] + bv1;
                        float e0 = __expf(2.f * v0);
                        float e1 = __expf(2.f * v1);
                        f16x2 ov;
                        ov[0] = (_Float16)(10.f * (1.f - 2.f / (e0 + 1.f)));
                        ov[1] = (_Float16)(10.f * (1.f - 2.f / (e1 + 1.f)));
                        *(f16x2*)(off2 + (((size_t)(b * 16 + g) * 9 + k) * HW + pxbase + px) * 2) = ov;
                    }
                } else if (co0 < 432) {      // two mask channels
                    #pragma unroll
                    for (int j = 0; j < 2; ++j) {
                        int co = co0 + j;
                        int mm = co - 288;
                        int g = mm / 9;
                        int k = mm - g * 9;
                        float bv = bias[co];
                        #pragma unroll
                        for (int nt = 0; nt < NT; ++nt) {
                            int px = (wv_n * NT + nt) * 16 + l16;
                            float v = acc[mt][nt][2 * r2 + j] + bv;
                            v = 1.f / (1.f + __expf(-v));
                            mskp[((size_t)(b * 16 + g) * 9 + k) * HW + pxbase + px] = (_Float16)v;
                        }
                    }
                }
            }
        }
    }
}

// ---------------------------------------------------------------------------
// FUSED deformable conv, 64-px geometry + issue-all/finish-all gathers
// (r7-verified). issue(gl+1) fires during MFMA(gl); double-buffered LDS.
// ---------------------------------------------------------------------------
__global__ __launch_bounds__(256, 4)
void deform_fused(const _Float16* __restrict__ xt, const _Float16* __restrict__ off2,
                  const _Float16* __restrict__ msk, const _Float16* __restrict__ wp,
                  const float* __restrict__ bias, float* __restrict__ out) {
    __shared__ __align__(16) char vlds[2 * 64 * 256];   // 32 KB, double-buffered
    const int tid  = threadIdx.x;
    const int bx   = (blockIdx.x & 7) * 128 + (blockIdx.x >> 3);
    const int ns   = bx & 1;
    const int bh   = bx >> 1;
    const int b    = bh >> 7;
    const int hrow = bh & 127;
    const int wv   = tid >> 6;
    const int lane = tid & 63;
    const int quad = lane >> 4;
    const int l16  = lane & 15;

    const int pxl   = tid & 63;        // local px (V row)
    const int kq    = tid >> 6;        // k-quarter (wave-uniform)
    const int wglob = ns * 64 + pxl;
    const int pxg   = hrow * 128 + wglob;

    {   // zero both buffers: swizzled chunks (9..11)^sw are never written
        f32x4 z = (f32x4){0.f, 0.f, 0.f, 0.f};
        for (int i = tid; i < 2048; i += 256) ((f32x4*)vlds)[i] = z;
    }
    __syncthreads();

    const _Float16* o2b = off2 + (size_t)b * 16 * 9 * HW * 2;
    const _Float16* mb  = msk  + (size_t)b * 16 * 9 * HW;

    f32x4 acc[4];
    #pragma unroll
    for (int nt = 0; nt < 4; ++nt) acc[nt] = (f32x4){0.f, 0.f, 0.f, 0.f};

    // LDS chunk byte offsets are group-invariant
    int ch[3];
    #pragma unroll
    for (int i = 0; i < 3; ++i) ch[i] = (((kq + 4 * i) ^ (pxl & 15)) << 4);

    // in-flight gather state (3 taps x 4 corners)
    f16x8 g00[3], g01[3], g10[3], g11[3];
    _Float16 h00[3], h01[3], h10[3], h11[3];

    // issue: compute all tap addrs+weights, fire all loads (no consumers here)
    auto issue = [&](int gl, const f16x2* od, const _Float16* m) {
        const _Float16* xg = xt + ((size_t)(b * 16 + gl) * HW) * 8;
        #pragma unroll
        for (int i = 0; i < 3; ++i) {
            int k = kq + 4 * i;
            if (k < 9) {
                float dy = (float)od[i][0];
                float dx = (float)od[i][1];
                float mm = (float)m[i];
                float py  = (float)(hrow - 1 + k / 3) + dy;
                float pxf = (float)(wglob - 1 + k % 3) + dx;
                float y0f = floorf(py), x0f = floorf(pxf);
                float ly = py - y0f, lx = pxf - x0f;
                int y0 = (int)y0f, x0 = (int)x0f;
                int y1 = y0 + 1,  x1 = x0 + 1;
                float vy0 = ((unsigned)y0 < 128u) ? 1.f : 0.f;
                float vy1 = ((unsigned)y1 < 128u) ? 1.f : 0.f;
                float vx0 = ((unsigned)x0 < 128u) ? 1.f : 0.f;
                float vx1 = ((unsigned)x1 < 128u) ? 1.f : 0.f;
                h00[i] = (_Float16)((1.f - ly) * (1.f - lx) * vy0 * vx0 * mm);
                h01[i] = (_Float16)((1.f - ly) * lx         * vy0 * vx1 * mm);
                h10[i] = (_Float16)(ly * (1.f - lx)         * vy1 * vx0 * mm);
                h11[i] = (_Float16)(ly * lx                 * vy1 * vx1 * mm);
                int yc0 = min(max(y0, 0), 127), yc1 = min(max(y1, 0), 127);
                int xc0 = min(max(x0, 0), 127), xc1 = min(max(x1, 0), 127);
                g00[i] = *(const f16x8*)(xg + (yc0 * W_ + xc0) * 8);
                g01[i] = *(const f16x8*)(xg + (yc0 * W_ + xc1) * 8);
                g10[i] = *(const f16x8*)(xg + (yc1 * W_ + xc0) * 8);
                g11[i] = *(const f16x8*)(xg + (yc1 * W_ + xc1) * 8);
            }
        }
    };

    // finish: lerp all taps, write V tile
    auto finish = [&](int gl) {
        char* vb = vlds + (gl & 1) * 16384;
        #pragma unroll
        for (int i = 0; i < 3; ++i) {
            int k = kq + 4 * i;
            if (k < 9) {
                f16x8 vv = g00[i] * h00[i] + g01[i] * h01[i]
                         + g10[i] * h10[i] + g11[i] * h11[i];   // v_pk_fma_f16
                *(f16x8*)(vb + pxl * 256 + ch[i]) = vv;
            }
        }
    };

    // prologue: offsets + gathers for group 0
    {
        f16x2 od0[3]; _Float16 m0[3];
        #pragma unroll
        for (int i = 0; i < 3; ++i) {
            od0[i] = (f16x2){0, 0}; m0[i] = (_Float16)0.f;
            int k = kq + 4 * i;
            if (k < 9) {
                od0[i] = *(const f16x2*)(o2b + ((size_t)k * HW + pxg) * 2);
                m0[i]  = mb[(size_t)k * HW + pxg];
            }
        }
        issue(0, od0, m0);
    }

    #pragma unroll 1
    for (int gl = 0; gl < 16; ++gl) {
        // prefetch offsets/masks for gl+1 (independent; long latency OK)
        f16x2 od_n[3]; _Float16 m_n[3];
        #pragma unroll
        for (int i = 0; i < 3; ++i) { od_n[i] = (f16x2){0, 0}; m_n[i] = (_Float16)0.f; }
        if (gl < 15) {
            #pragma unroll
            for (int i = 0; i < 3; ++i) {
                int k = kq + 4 * i;
                if (k < 9) {
                    od_n[i] = *(const f16x2*)(o2b + ((size_t)((gl + 1) * 9 + k) * HW + pxg) * 2);
                    m_n[i]  = mb[(size_t)((gl + 1) * 9 + k) * HW + pxg];
                }
            }
        }

        // weight fragments for this group (L2-resident)
        f16x8 aF[3];
        const _Float16* wg = wp + ((size_t)(gl * 64 + wv * 16 + l16)) * 96 + quad * 8;
        #pragma unroll
        for (int s = 0; s < 3; ++s) aF[s] = *(const f16x8*)(wg + s * 32);

        finish(gl);                    // wait gathers, lerp, write vb[gl&1]
        __syncthreads();

        if (gl < 15) issue(gl + 1, od_n, m_n);   // loads fly during MFMA

        char* vb = vlds + (gl & 1) * 16384;
        #pragma unroll
        for (int nt = 0; nt < 4; ++nt) {
            int row = nt * 16 + l16;
            int sw  = row & 15;
            #pragma unroll
            for (int s = 0; s < 3; ++s) {
                f16x8 bF = *(const f16x8*)(vb + row * 256 + (((s << 2) + quad) ^ sw) * 16);
                acc[nt] = __builtin_amdgcn_mfma_f32_16x16x32_f16(aF[s], bF, acc[nt], 0, 0, 0);
            }
        }
    }

    // ---- epilogue: transpose 64co x 64px through LDS, coalesced fp32 stores
    __syncthreads();
    float* vf = (float*)vlds;
    #pragma unroll
    for (int r = 0; r < 4; ++r) {
        int o = wv * 16 + quad * 4 + r;
        #pragma unroll
        for (int nt = 0; nt < 4; ++nt) {
            int col = nt ^ quad;
            vf[o * 64 + col * 16 + l16] = acc[nt][r];
        }
    }
    __syncthreads();
    float* ob = out + ((size_t)(b * 64)) * HW + hrow * 128 + ns * 64;
    #pragma unroll
    for (int it = 0; it < 4; ++it) {
        int slot = tid + it * 256;
        int o    = slot >> 4;
        int p4   = slot & 15;
        int col  = (p4 >> 2) ^ ((o >> 2) & 3);
        f32x4 v = *(const f32x4*)(vf + o * 64 + col * 16 + (p4 & 3) * 4);
        float bv = bias[o];
        float4 sv = make_float4(v[0] + bv, v[1] + bv, v[2] + bv, v[3] + bv);
        *(float4*)(ob + (size_t)o * HW + p4 * 4) = sv;
    }
}

// ---------------------------------------------------------------------------
extern "C" void kernel_launch(void* const* d_in, const int* in_sizes, int n_in,
                              void* d_out, int out_size, void* d_ws, size_t ws_size,
                              hipStream_t stream) {
    const float* x  = (const float*)d_in[0];
    const float* ef = (const float*)d_in[1];
    const float* w1 = (const float*)d_in[2];
    const float* b1 = (const float*)d_in[3];
    const float* w2 = (const float*)d_in[4];
    const float* b2 = (const float*)d_in[5];
    const float* w3 = (const float*)d_in[6];
    const float* b3 = (const float*)d_in[7];
    const float* w4 = (const float*)d_in[8];
    const float* b4 = (const float*)d_in[9];
    const float* wd = (const float*)d_in[10];
    const float* bd = (const float*)d_in[11];
    float* out = (float*)d_out;

    char* ws = (char*)d_ws;
    _Float16* ef_t = (_Float16*)(ws);                     // 25,165,824 B
    _Float16* tA   = (_Float16*)(ws + 25165824);          //  8,388,608 B
    _Float16* tB   = (_Float16*)(ws + 33554432);          //  8,388,608 B
    _Float16* off2 = (_Float16*)(ws + 41943040);          // 37,748,736 B
    _Float16* mskb = (_Float16*)(ws + 79691776);          // 18,874,368 B
    _Float16* wpd  = (_Float16*)(ws + 98566144);          //    196,608 B
    _Float16* A1   = (_Float16*)(ws + 98762752);          //    221,184 B
    _Float16* A2   = (_Float16*)(ws + 98983936);          //     73,728 B
    _Float16* A3   = (_Float16*)(ws + 99057664);          //     73,728 B
    _Float16* A4   = (_Float16*)(ws + 99131392);          //    589,824 B
    _Float16* xtb  = (_Float16*)(ws + 99721216);          // 16,777,216 B -> ends 116,498,432

    prep_all<<<6864, 256, 0, stream>>>(wd, w1, w2, w3, w4, x, ef,
                                       wpd, A1, A2, A3, A4, xtb, ef_t);

    //            CIN  COUT COpad NWM NWN MT NT ACT MINW
    conv_mfma2<192,  64,  64,  2,  2, 2, 2, 1, 4><<<dim3(1024, 1), 256, 0, stream>>>(ef_t, A1, b1, tA, nullptr);
    conv_mfma2< 64,  64,  64,  2,  2, 2, 2, 1, 4><<<dim3(1024, 1), 256, 0, stream>>>(tA, A2, b2, tB, nullptr);
    conv_mfma2< 64,  64,  64,  2,  2, 2, 2, 1, 4><<<dim3(1024, 1), 256, 0, stream>>>(tB, A3, b3, tA, nullptr);
    conv_mfma2< 64, 432, 512,  4,  1, 4, 4, 2, 3><<<dim3(1024, 2), 256, 0, stream>>>(tA, A4, b4, off2, mskb);

    deform_fused<<<1024, 256, 0, stream>>>(xtb, off2, mskb, wpd, bd, out);
}